// Round 1
// 503.198 us; speedup vs baseline: 1.2744x; 1.2744x over previous
//
#include <hip/hip_runtime.h>
#include <hip/hip_bf16.h>
#include <math.h>

typedef __attribute__((ext_vector_type(8))) short bf16x8;
typedef __attribute__((ext_vector_type(4))) float f32x4;

#define MTOT  131072
#define HW16K 16384

__device__ inline float bf2f(unsigned short u) {
    union { unsigned u; float f; } x; x.u = ((unsigned)u) << 16; return x.f;
}
__device__ inline unsigned short f2bf(float a) {
    __hip_bfloat16 h = __float2bfloat16(a);
    union { __hip_bfloat16 h; unsigned short u; } c; c.h = h; return c.u;
}
__device__ inline unsigned pack2bf(float a, float b) {
    __hip_bfloat162 h = __float22bfloat162_rn(make_float2(a, b));
    union { __hip_bfloat162 h; unsigned u; } c; c.h = h; return c.u;
}
__device__ inline void load16(const unsigned short* p, float* f) {
    uint4 u0 = *(const uint4*)p;
    uint4 u1 = *(const uint4*)(p + 8);
    unsigned w[8] = {u0.x, u0.y, u0.z, u0.w, u1.x, u1.y, u1.z, u1.w};
#pragma unroll
    for (int i = 0; i < 8; i++) {
        union { unsigned u; float f; } lo, hi;
        lo.u = w[i] << 16; hi.u = w[i] & 0xffff0000u;
        f[2 * i] = lo.f; f[2 * i + 1] = hi.f;
    }
}

// ------------------------------------------------ weights fp32 -> bf16
// qkv weight rows are PERMUTED so qkv GEMM output per pixel is
// [g=di*2+hd][q16|k16|v16] (6 groups x 48 channels) -> contiguous attn reads.
__global__ __launch_bounds__(256) void k_prep(const float* __restrict__ qw,
                                              const float* __restrict__ pw,
                                              const float* __restrict__ f1,
                                              const float* __restrict__ f2,
                                              unsigned short* __restrict__ wq,
                                              unsigned short* __restrict__ wp,
                                              unsigned short* __restrict__ w1,
                                              unsigned short* __restrict__ w2) {
    int t = blockIdx.x * 256 + threadIdx.x;
    if (t < 27648) {
        int row = t / 96, col = t - row * 96;
        int s = row / 96;            // 0=q 1=k 2=v
        int rem = row - s * 96;
        int di = rem >> 5;
        int hd = (rem >> 4) & 1;
        int c  = rem & 15;
        int nrow = (di * 2 + hd) * 48 + s * 16 + c;
        wq[nrow * 96 + col] = f2bf(qw[t]);
    }
    else if (t < 36864) wp[t - 27648] = f2bf(pw[t - 27648]);
    else if (t < 73728) w1[t - 36864] = f2bf(f1[t - 36864]);
    else if (t < 110592) w2[t - 73728] = f2bf(f2[t - 73728]);
}

// ------------------------------------------------ LN1: planar x -> pixel-major y bf16
__global__ __launch_bounds__(256) void k_ln1(const float* __restrict__ x,
                                             const float* __restrict__ w,
                                             const float* __restrict__ bln,
                                             unsigned* __restrict__ y) {
    __shared__ float buf[128 * 97];
    __shared__ float ps[256], ps2[256];
    int tid = threadIdx.x;
    int p = tid & 127, half = tid >> 7;
    int gp0 = blockIdx.x * 128;
    int b = gp0 >> 14, pix0 = gp0 & 16383;

    float val[48];
    float s = 0.f, s2 = 0.f;
#pragma unroll
    for (int i = 0; i < 48; i++) {
        int c = half * 48 + i;
        float v = x[((size_t)b * 96 + c) * HW16K + pix0 + p];
        val[i] = v; s += v; s2 += v * v;
    }
    ps[tid] = s; ps2[tid] = s2;
    __syncthreads();
    float st = ps[p] + ps[p + 128];
    float st2 = ps2[p] + ps2[p + 128];
    float mu = st * (1.f / 96.f);
    float inv = rsqrtf(st2 * (1.f / 96.f) - mu * mu + 1e-5f);
#pragma unroll
    for (int i = 0; i < 48; i++) {
        int c = half * 48 + i;
        buf[p * 97 + c] = (val[i] - mu) * inv * w[c] + bln[c];
    }
    __syncthreads();
#pragma unroll 1
    for (int it = 0; it < 24; it++) {
        int w2 = it * 256 + tid;
        int pp = w2 / 48, cp = w2 % 48;
        float f0 = buf[pp * 97 + cp * 2];
        float f1 = buf[pp * 97 + cp * 2 + 1];
        y[(size_t)gp0 * 48 + w2] = pack2bf(f0, f1);
    }
}

// ------------------------------------------------ MFMA GEMM, swapped operands.
// A: [m][K] bf16 pixel-major.  Bw: [N][K] bf16 (weights, row = out channel).
// mfma(W_frag, P_frag): D[och][px], lane holds px = lane&15 fixed and
// och = nt*16 + (lane>>4)*4 + r  -> 4 consecutive channels of ONE pixel
// -> coalescable 8B uint2 stores into [px][N] bf16.
// EPI: 0 = store; 1 = +bias; 2 = +bias +GeLU.
template<int N, int K, int NW, int TPW, int EPI>
__global__ __launch_bounds__(NW * 64) void k_gemm(const unsigned short* __restrict__ A,
                                                  const unsigned short* __restrict__ Bw,
                                                  const float* __restrict__ bias,
                                                  unsigned short* __restrict__ out) {
    constexpr int KF = K / 32, NT = N / 16;
    __shared__ unsigned short Bs[N * K];
    int tid = threadIdx.x;
    for (int i = tid; i < N * K / 8; i += NW * 64)
        ((uint4*)Bs)[i] = ((const uint4*)Bw)[i];
    __syncthreads();

    int lane = tid & 63, wv = tid >> 6;
    int kq = (lane >> 4) * 8;

#pragma unroll 1
    for (int it = 0; it < TPW; it++) {
        int pt = blockIdx.x * (NW * TPW) + wv * TPW + it;
        int px = pt * 16 + (lane & 15);

        bf16x8 p[KF];
        const unsigned short* ar = A + (size_t)px * K + kq;
#pragma unroll
        for (int f = 0; f < KF; f++) p[f] = *(const bf16x8*)(ar + f * 32);

        f32x4 acc[NT];
#pragma unroll
        for (int nt = 0; nt < NT; nt++) acc[nt] = (f32x4){0.f, 0.f, 0.f, 0.f};

#pragma unroll
        for (int nt = 0; nt < NT; nt++) {
            const unsigned short* br = Bs + (nt * 16 + (lane & 15)) * K + kq;
#pragma unroll
            for (int f = 0; f < KF; f++) {
                bf16x8 wf = *(const bf16x8*)(br + f * 32);
                acc[nt] = __builtin_amdgcn_mfma_f32_16x16x32_bf16(wf, p[f], acc[nt], 0, 0, 0);
            }
        }

        unsigned short* orow = out + (size_t)px * N + (lane >> 4) * 4;
#pragma unroll
        for (int nt = 0; nt < NT; nt++) {
            float r0 = acc[nt][0], r1 = acc[nt][1], r2 = acc[nt][2], r3 = acc[nt][3];
            if constexpr (EPI != 0) {
                float4 bb = ((const float4*)bias)[nt * 4 + (lane >> 4)];
                r0 += bb.x; r1 += bb.y; r2 += bb.z; r3 += bb.w;
            }
            if constexpr (EPI == 2) {
                r0 = 0.5f * r0 * (1.f + erff(r0 * 0.70710678118654752f));
                r1 = 0.5f * r1 * (1.f + erff(r1 * 0.70710678118654752f));
                r2 = 0.5f * r2 * (1.f + erff(r2 * 0.70710678118654752f));
                r3 = 0.5f * r3 * (1.f + erff(r3 * 0.70710678118654752f));
            }
            uint2 pk;
            pk.x = pack2bf(r0, r1);
            pk.y = pack2bf(r2, r3);
            *(uint2*)(orow + nt * 16) = pk;
        }
    }
}

// ------------------------------------------------ dilated attention, full-M
// qkvb: [px][288] = 6 groups x (q16|k16|v16). One thread per (px, g).
// grid(6, 512) x 256: consecutive blocks share px range (L2/L3 locality).
__global__ __launch_bounds__(256) void k_attn(const unsigned short* __restrict__ qkvb,
                                              unsigned short* __restrict__ attnb) {
    int g = blockIdx.x;                       // di*2+hd
    int px = blockIdx.y * 256 + threadIdx.x;
    int d = (g >> 1) + 1;
    int pix = px & 16383;
    int hh = pix >> 7, ww = pix & 127;
    int ibase = px & ~16383;
    const unsigned short* base = qkvb + (size_t)px * 288 + g * 48;

    float q[16];
    load16(base, q);

    float sc[9]; int nloc[9]; bool ok[9];
#pragma unroll
    for (int i = 0; i < 3; i++) {
#pragma unroll
        for (int j = 0; j < 3; j++) {
            int k9 = i * 3 + j;
            int yy = hh + (i - 1) * d;
            int xx = ww + (j - 1) * d;
            bool o_ = ((unsigned)yy < 128u) && ((unsigned)xx < 128u);
            ok[k9] = o_;
            nloc[k9] = ibase + yy * 128 + xx;
            float s = 0.f;
            if (o_) {
                float kf[16];
                load16(qkvb + (size_t)nloc[k9] * 288 + g * 48 + 16, kf);
#pragma unroll
                for (int c = 0; c < 16; c++) s += q[c] * kf[c];
            }
            sc[k9] = s * 0.25f;
        }
    }
    float mx = sc[0];
#pragma unroll
    for (int k9 = 1; k9 < 9; k9++) mx = fmaxf(mx, sc[k9]);
    float sum = 0.f;
#pragma unroll
    for (int k9 = 0; k9 < 9; k9++) { sc[k9] = __expf(sc[k9] - mx); sum += sc[k9]; }
    float rs = 1.f / sum;

    float o[16];
#pragma unroll
    for (int c = 0; c < 16; c++) o[c] = 0.f;
#pragma unroll
    for (int k9 = 0; k9 < 9; k9++) {
        if (ok[k9]) {
            float vf[16];
            load16(qkvb + (size_t)nloc[k9] * 288 + g * 48 + 32, vf);
            float w9 = sc[k9];
#pragma unroll
            for (int c = 0; c < 16; c++) o[c] += w9 * vf[c];
        }
    }
    // output channel base = di*32 + hd*16 = g*16
    unsigned* orow = (unsigned*)(attnb + (size_t)px * 96 + g * 16);
    uint4 pk0;
    pk0.x = pack2bf(o[0] * rs, o[1] * rs);
    pk0.y = pack2bf(o[2] * rs, o[3] * rs);
    pk0.z = pack2bf(o[4] * rs, o[5] * rs);
    pk0.w = pack2bf(o[6] * rs, o[7] * rs);
    ((uint4*)orow)[0] = pk0;
    uint4 pk1;
    pk1.x = pack2bf(o[8] * rs, o[9] * rs);
    pk1.y = pack2bf(o[10] * rs, o[11] * rs);
    pk1.z = pack2bf(o[12] * rs, o[13] * rs);
    pk1.w = pack2bf(o[14] * rs, o[15] * rs);
    ((uint4*)orow)[1] = pk1;
}

// ------------------------------------------------ residual + LN2 fused.
// x planar fp32 (coalesced), pout pixel-major bf16 rows -> y2 pixel-major bf16.
__global__ __launch_bounds__(256) void k_res_ln2(const float* __restrict__ x,
                                                 const unsigned short* __restrict__ pout,
                                                 const float* __restrict__ w,
                                                 const float* __restrict__ bln,
                                                 unsigned* __restrict__ y2) {
    int px = blockIdx.x * 256 + threadIdx.x;
    int b = px >> 14, pix = px & 16383;
    const float* xp = x + (size_t)b * 96 * HW16K + pix;
    const uint4* pr = (const uint4*)(pout + (size_t)px * 96);
    float v[96];
    float s = 0.f, s2 = 0.f;
#pragma unroll
    for (int i = 0; i < 12; i++) {
        uint4 t = pr[i];
        unsigned wd[4] = {t.x, t.y, t.z, t.w};
#pragma unroll
        for (int u = 0; u < 4; u++) {
            int c = i * 8 + u * 2;
            float p0 = bf2f((unsigned short)(wd[u] & 0xffffu));
            float p1 = bf2f((unsigned short)(wd[u] >> 16));
            float v0 = p0 + xp[(size_t)c * HW16K];
            float v1 = p1 + xp[(size_t)(c + 1) * HW16K];
            v[c] = v0; v[c + 1] = v1;
            s += v0 + v1; s2 += v0 * v0 + v1 * v1;
        }
    }
    float mu = s * (1.f / 96.f);
    float inv = rsqrtf(s2 * (1.f / 96.f) - mu * mu + 1e-5f);
    unsigned* yr = y2 + (size_t)px * 48;
#pragma unroll
    for (int j = 0; j < 12; j++) {
        int c = j * 8;
        uint4 pk;
        pk.x = pack2bf((v[c + 0] - mu) * inv * w[c + 0] + bln[c + 0],
                       (v[c + 1] - mu) * inv * w[c + 1] + bln[c + 1]);
        pk.y = pack2bf((v[c + 2] - mu) * inv * w[c + 2] + bln[c + 2],
                       (v[c + 3] - mu) * inv * w[c + 3] + bln[c + 3]);
        pk.z = pack2bf((v[c + 4] - mu) * inv * w[c + 4] + bln[c + 4],
                       (v[c + 5] - mu) * inv * w[c + 5] + bln[c + 5]);
        pk.w = pack2bf((v[c + 6] - mu) * inv * w[c + 6] + bln[c + 6],
                       (v[c + 7] - mu) * inv * w[c + 7] + bln[c + 7]);
        ((uint4*)yr)[j] = pk;
    }
}

// ------------------------------------------------ final: out = x + pout + mlp (planar)
__global__ __launch_bounds__(256) void k_final(const float* __restrict__ x,
                                               const unsigned short* __restrict__ pout,
                                               const unsigned short* __restrict__ mlp,
                                               float* __restrict__ out) {
    int px = blockIdx.x * 256 + threadIdx.x;
    int b = px >> 14, pix = px & 16383;
    const float* xp = x + (size_t)b * 96 * HW16K + pix;
    float* op = out + (size_t)b * 96 * HW16K + pix;
    const uint4* pr = (const uint4*)(pout + (size_t)px * 96);
    const uint4* mr = (const uint4*)(mlp + (size_t)px * 96);
#pragma unroll
    for (int i = 0; i < 12; i++) {
        uint4 tp = pr[i], tm = mr[i];
        unsigned wpx[4] = {tp.x, tp.y, tp.z, tp.w};
        unsigned wmx[4] = {tm.x, tm.y, tm.z, tm.w};
#pragma unroll
        for (int u = 0; u < 4; u++) {
            int c = i * 8 + u * 2;
            op[(size_t)c * HW16K] = xp[(size_t)c * HW16K]
                + bf2f((unsigned short)(wpx[u] & 0xffffu))
                + bf2f((unsigned short)(wmx[u] & 0xffffu));
            op[(size_t)(c + 1) * HW16K] = xp[(size_t)(c + 1) * HW16K]
                + bf2f((unsigned short)(wpx[u] >> 16))
                + bf2f((unsigned short)(wmx[u] >> 16));
        }
    }
}

// ------------------------------------------------ launch
extern "C" void kernel_launch(void* const* d_in, const int* in_sizes, int n_in,
                              void* d_out, int out_size, void* d_ws, size_t ws_size,
                              hipStream_t stream) {
    const float* x      = (const float*)d_in[0];
    const float* qkv_w  = (const float*)d_in[1];
    const float* proj_w = (const float*)d_in[2];
    const float* proj_b = (const float*)d_in[3];
    const float* ln1w   = (const float*)d_in[4];
    const float* ln1b   = (const float*)d_in[5];
    const float* ln2w   = (const float*)d_in[6];
    const float* ln2b   = (const float*)d_in[7];
    const float* fc1w   = (const float*)d_in[8];
    const float* fc1b   = (const float*)d_in[9];
    const float* fc2w   = (const float*)d_in[10];
    const float* fc2b   = (const float*)d_in[11];
    float* out = (float*)d_out;

    char* ws = (char*)d_ws;
    unsigned short* wq = (unsigned short*)(ws);              // 55296 B
    unsigned short* wp = (unsigned short*)(ws + 55296);      // 18432 B
    unsigned short* w1 = (unsigned short*)(ws + 73728);      // 73728 B
    unsigned short* w2 = (unsigned short*)(ws + 147456);     // 73728 B
    // region Y (25.17 MB): y -> attnb -> y2 -> mlp_out
    unsigned short* y    = (unsigned short*)(ws + 221184);
    // region Q (75.5 MB): qkvb; after attention it is dead and hosts pout|h
    unsigned short* qkvb = (unsigned short*)(ws + 25387008);
    unsigned short* pout = qkvb;                              // 25.17 MB
    unsigned short* h    = (unsigned short*)(ws + 50552832);  // 25.17 MB
    // total ws = 100884480 B (~101 MB)

    k_prep<<<432, 256, 0, stream>>>(qkv_w, proj_w, fc1w, fc2w, wq, wp, w1, w2);
    k_ln1<<<1024, 256, 0, stream>>>(x, ln1w, ln1b, (unsigned*)y);

    // qkv GEMM, full M: 8192 pixel-tiles = 512 blocks * 8 waves * 2 tiles
    k_gemm<288, 96, 8, 2, 0><<<512, 512, 0, stream>>>(y, wq, nullptr, qkvb);
    // attention, full M; attnb reuses region Y (y is dead after qkv GEMM)
    k_attn<<<dim3(6, 512), 256, 0, stream>>>(qkvb, y);
    // proj (+bias) -> pout bf16 pixel-major (qkvb dead, reuse)
    k_gemm<96, 96, 8, 1, 1><<<1024, 512, 0, stream>>>(y, wp, proj_b, pout);
    // residual + LN2 -> y2 (region Y)
    k_res_ln2<<<512, 256, 0, stream>>>(x, pout, ln2w, ln2b, (unsigned*)y);

    // MLP: 4 chunks of 32768 pixels; h chunk stays L2/L3-resident,
    // mlp_out overwrites the already-consumed y2 chunk in region Y.
    for (int c = 0; c < 4; c++) {
        size_t m0 = (size_t)c * 32768;
        k_gemm<384, 96, 8, 1, 2><<<256, 512, 0, stream>>>(y + m0 * 96, w1, fc1b, h);
        k_gemm<96, 384, 8, 1, 1><<<256, 512, 0, stream>>>(h, w2, fc2b, y + m0 * 96);
    }
    // out = x + pout + mlp, all coalesced
    k_final<<<512, 256, 0, stream>>>(x, pout, y, out);
}

// Round 2
// 401.556 us; speedup vs baseline: 1.5970x; 1.2531x over previous
//
#include <hip/hip_runtime.h>
#include <hip/hip_bf16.h>
#include <math.h>

typedef __attribute__((ext_vector_type(8))) short bf16x8;
typedef __attribute__((ext_vector_type(4))) float f32x4;

#define MTOT  131072
#define HW16K 16384

__device__ inline float bf2f(unsigned short u) {
    union { unsigned u; float f; } x; x.u = ((unsigned)u) << 16; return x.f;
}
__device__ inline unsigned short f2bf(float a) {
    __hip_bfloat16 h = __float2bfloat16(a);
    union { __hip_bfloat16 h; unsigned short u; } c; c.h = h; return c.u;
}
__device__ inline unsigned pack2bf(float a, float b) {
    __hip_bfloat162 h = __float22bfloat162_rn(make_float2(a, b));
    union { __hip_bfloat162 h; unsigned u; } c; c.h = h; return c.u;
}
__device__ inline void load16(const unsigned short* p, float* f) {
    uint4 u0 = *(const uint4*)p;
    uint4 u1 = *(const uint4*)(p + 8);
    unsigned w[8] = {u0.x, u0.y, u0.z, u0.w, u1.x, u1.y, u1.z, u1.w};
#pragma unroll
    for (int i = 0; i < 8; i++) {
        union { unsigned u; float f; } lo, hi;
        lo.u = w[i] << 16; hi.u = w[i] & 0xffff0000u;
        f[2 * i] = lo.f; f[2 * i + 1] = hi.f;
    }
}

// ------------------------------------------------ weights fp32 -> bf16
// qkv weight rows are PERMUTED to nrow = s*96 + (di*2+hd)*16 + c so that the
// qkv GEMM's output 16-channel block index (och>>4) == plane s*6+g directly.
__global__ __launch_bounds__(256) void k_prep(const float* __restrict__ qw,
                                              const float* __restrict__ pw,
                                              const float* __restrict__ f1,
                                              const float* __restrict__ f2,
                                              unsigned short* __restrict__ wq,
                                              unsigned short* __restrict__ wp,
                                              unsigned short* __restrict__ w1,
                                              unsigned short* __restrict__ w2) {
    int t = blockIdx.x * 256 + threadIdx.x;
    if (t < 27648) {
        int row = t / 96, col = t - row * 96;
        int s = row / 96;            // 0=q 1=k 2=v
        int rem = row - s * 96;
        int di = rem >> 5;
        int hd = (rem >> 4) & 1;
        int c  = rem & 15;
        int nrow = s * 96 + (di * 2 + hd) * 16 + c;   // plane (s*6+g), chan c
        wq[nrow * 96 + col] = f2bf(qw[t]);
    }
    else if (t < 36864) wp[t - 27648] = f2bf(pw[t - 27648]);
    else if (t < 73728) w1[t - 36864] = f2bf(f1[t - 36864]);
    else if (t < 110592) w2[t - 73728] = f2bf(f2[t - 73728]);
}

// ------------------------------------------------ LN1: planar x -> pixel-major y bf16
__global__ __launch_bounds__(256) void k_ln1(const float* __restrict__ x,
                                             const float* __restrict__ w,
                                             const float* __restrict__ bln,
                                             unsigned* __restrict__ y) {
    __shared__ float buf[128 * 97];
    __shared__ float ps[256], ps2[256];
    int tid = threadIdx.x;
    int p = tid & 127, half = tid >> 7;
    int gp0 = blockIdx.x * 128;
    int b = gp0 >> 14, pix0 = gp0 & 16383;

    float val[48];
    float s = 0.f, s2 = 0.f;
#pragma unroll
    for (int i = 0; i < 48; i++) {
        int c = half * 48 + i;
        float v = x[((size_t)b * 96 + c) * HW16K + pix0 + p];
        val[i] = v; s += v; s2 += v * v;
    }
    ps[tid] = s; ps2[tid] = s2;
    __syncthreads();
    float st = ps[p] + ps[p + 128];
    float st2 = ps2[p] + ps2[p + 128];
    float mu = st * (1.f / 96.f);
    float inv = rsqrtf(st2 * (1.f / 96.f) - mu * mu + 1e-5f);
#pragma unroll
    for (int i = 0; i < 48; i++) {
        int c = half * 48 + i;
        buf[p * 97 + c] = (val[i] - mu) * inv * w[c] + bln[c];
    }
    __syncthreads();
#pragma unroll 1
    for (int it = 0; it < 24; it++) {
        int w2 = it * 256 + tid;
        int pp = w2 / 48, cp = w2 % 48;
        float f0 = buf[pp * 97 + cp * 2];
        float f1 = buf[pp * 97 + cp * 2 + 1];
        y[(size_t)gp0 * 48 + w2] = pack2bf(f0, f1);
    }
}

// ------------------------------------------------ MFMA GEMM, swapped operands.
// A: [m][K] bf16 pixel-major.  Bw: [N][K] bf16 (weights, row = out channel).
// mfma(W_frag, P_frag): lane holds px = lane&15, och = nt*16 + (lane>>4)*4 + r.
// EPI: 0 = store [px][N]; 1 = +bias [px][N]; 2 = +bias +GeLU [px][N];
//      3 = qkv planar store: plane nt (= s*6+g), addr ((nt*MTOT+px)*16 + quad).
template<int N, int K, int NW, int TPW, int EPI>
__global__ __launch_bounds__(NW * 64) void k_gemm(const unsigned short* __restrict__ A,
                                                  const unsigned short* __restrict__ Bw,
                                                  const float* __restrict__ bias,
                                                  unsigned short* __restrict__ out) {
    constexpr int KF = K / 32, NT = N / 16;
    __shared__ unsigned short Bs[N * K];
    int tid = threadIdx.x;
    for (int i = tid; i < N * K / 8; i += NW * 64)
        ((uint4*)Bs)[i] = ((const uint4*)Bw)[i];
    __syncthreads();

    int lane = tid & 63, wv = tid >> 6;
    int kq = (lane >> 4) * 8;

#pragma unroll 1
    for (int it = 0; it < TPW; it++) {
        int pt = blockIdx.x * (NW * TPW) + wv * TPW + it;
        int px = pt * 16 + (lane & 15);

        bf16x8 p[KF];
        const unsigned short* ar = A + (size_t)px * K + kq;
#pragma unroll
        for (int f = 0; f < KF; f++) p[f] = *(const bf16x8*)(ar + f * 32);

        f32x4 acc[NT];
#pragma unroll
        for (int nt = 0; nt < NT; nt++) acc[nt] = (f32x4){0.f, 0.f, 0.f, 0.f};

#pragma unroll
        for (int nt = 0; nt < NT; nt++) {
            const unsigned short* br = Bs + (nt * 16 + (lane & 15)) * K + kq;
#pragma unroll
            for (int f = 0; f < KF; f++) {
                bf16x8 wf = *(const bf16x8*)(br + f * 32);
                acc[nt] = __builtin_amdgcn_mfma_f32_16x16x32_bf16(wf, p[f], acc[nt], 0, 0, 0);
            }
        }

#pragma unroll
        for (int nt = 0; nt < NT; nt++) {
            float r0 = acc[nt][0], r1 = acc[nt][1], r2 = acc[nt][2], r3 = acc[nt][3];
            if constexpr (EPI == 1 || EPI == 2) {
                float4 bb = ((const float4*)bias)[nt * 4 + (lane >> 4)];
                r0 += bb.x; r1 += bb.y; r2 += bb.z; r3 += bb.w;
            }
            if constexpr (EPI == 2) {
                r0 = 0.5f * r0 * (1.f + erff(r0 * 0.70710678118654752f));
                r1 = 0.5f * r1 * (1.f + erff(r1 * 0.70710678118654752f));
                r2 = 0.5f * r2 * (1.f + erff(r2 * 0.70710678118654752f));
                r3 = 0.5f * r3 * (1.f + erff(r3 * 0.70710678118654752f));
            }
            uint2 pk;
            pk.x = pack2bf(r0, r1);
            pk.y = pack2bf(r2, r3);
            if constexpr (EPI == 3) {
                *(uint2*)(out + ((size_t)nt * MTOT + px) * 16 + (lane >> 4) * 4) = pk;
            } else {
                *(uint2*)(out + (size_t)px * N + (lane >> 4) * 4 + nt * 16) = pk;
            }
        }
    }
}

// ------------------------------------------------ dilated attention, planar qkv
// qkvb: 18 planes [pl][px][16], pl = s*6+g (s: 0=q 1=k 2=v, g = di*2+hd).
// 3072 blocks, XCD-chunked: bid&7 (= XCD) gets a contiguous 64-block y-span
// per group g -> tap rows reused within one XCD's L2.
__global__ __launch_bounds__(256) void k_attn(const unsigned short* __restrict__ qkvb,
                                              unsigned short* __restrict__ attnb) {
    int bid = blockIdx.x;
    int xcd = bid & 7;
    int idx = bid >> 3;                  // 0..383
    int g   = idx >> 6;                  // 0..5
    int yb  = (xcd << 6) | (idx & 63);   // 0..511
    int px  = yb * 256 + threadIdx.x;

    int d = (g >> 1) + 1;
    int pix = px & 16383;
    int hh = pix >> 7, ww = pix & 127;
    int ibase = px & ~16383;

    const unsigned short* qpl = qkvb + (size_t)g * (MTOT * 16);
    const unsigned short* kpl = qkvb + (size_t)(6 + g) * (MTOT * 16);
    const unsigned short* vpl = qkvb + (size_t)(12 + g) * (MTOT * 16);

    float q[16];
    load16(qpl + (size_t)px * 16, q);

    float sc[9]; int nloc[9]; bool ok[9];
#pragma unroll
    for (int i = 0; i < 3; i++) {
#pragma unroll
        for (int j = 0; j < 3; j++) {
            int k9 = i * 3 + j;
            int yy = hh + (i - 1) * d;
            int xx = ww + (j - 1) * d;
            bool o_ = ((unsigned)yy < 128u) && ((unsigned)xx < 128u);
            ok[k9] = o_;
            nloc[k9] = ibase + yy * 128 + xx;
            float s = 0.f;
            if (o_) {
                float kf[16];
                load16(kpl + (size_t)nloc[k9] * 16, kf);
#pragma unroll
                for (int c = 0; c < 16; c++) s += q[c] * kf[c];
            }
            sc[k9] = s * 0.25f;
        }
    }
    float mx = sc[0];
#pragma unroll
    for (int k9 = 1; k9 < 9; k9++) mx = fmaxf(mx, sc[k9]);
    float sum = 0.f;
#pragma unroll
    for (int k9 = 0; k9 < 9; k9++) { sc[k9] = __expf(sc[k9] - mx); sum += sc[k9]; }
    float rs = 1.f / sum;

    float o[16];
#pragma unroll
    for (int c = 0; c < 16; c++) o[c] = 0.f;
#pragma unroll
    for (int k9 = 0; k9 < 9; k9++) {
        if (ok[k9]) {
            float vf[16];
            load16(vpl + (size_t)nloc[k9] * 16, vf);
            float w9 = sc[k9];
#pragma unroll
            for (int c = 0; c < 16; c++) o[c] += w9 * vf[c];
        }
    }
    // output channel base = di*32 + hd*16 = g*16 in [px][96] layout
    unsigned* orow = (unsigned*)(attnb + (size_t)px * 96 + g * 16);
    uint4 pk0;
    pk0.x = pack2bf(o[0] * rs, o[1] * rs);
    pk0.y = pack2bf(o[2] * rs, o[3] * rs);
    pk0.z = pack2bf(o[4] * rs, o[5] * rs);
    pk0.w = pack2bf(o[6] * rs, o[7] * rs);
    ((uint4*)orow)[0] = pk0;
    uint4 pk1;
    pk1.x = pack2bf(o[8] * rs, o[9] * rs);
    pk1.y = pack2bf(o[10] * rs, o[11] * rs);
    pk1.z = pack2bf(o[12] * rs, o[13] * rs);
    pk1.w = pack2bf(o[14] * rs, o[15] * rs);
    ((uint4*)orow)[1] = pk1;
}

// ------------------------------------------------ residual + LN2 fused.
__global__ __launch_bounds__(256) void k_res_ln2(const float* __restrict__ x,
                                                 const unsigned short* __restrict__ pout,
                                                 const float* __restrict__ w,
                                                 const float* __restrict__ bln,
                                                 unsigned* __restrict__ y2) {
    int px = blockIdx.x * 256 + threadIdx.x;
    int b = px >> 14, pix = px & 16383;
    const float* xp = x + (size_t)b * 96 * HW16K + pix;
    const uint4* pr = (const uint4*)(pout + (size_t)px * 96);
    float v[96];
    float s = 0.f, s2 = 0.f;
#pragma unroll
    for (int i = 0; i < 12; i++) {
        uint4 t = pr[i];
        unsigned wd[4] = {t.x, t.y, t.z, t.w};
#pragma unroll
        for (int u = 0; u < 4; u++) {
            int c = i * 8 + u * 2;
            float p0 = bf2f((unsigned short)(wd[u] & 0xffffu));
            float p1 = bf2f((unsigned short)(wd[u] >> 16));
            float v0 = p0 + xp[(size_t)c * HW16K];
            float v1 = p1 + xp[(size_t)(c + 1) * HW16K];
            v[c] = v0; v[c + 1] = v1;
            s += v0 + v1; s2 += v0 * v0 + v1 * v1;
        }
    }
    float mu = s * (1.f / 96.f);
    float inv = rsqrtf(s2 * (1.f / 96.f) - mu * mu + 1e-5f);
    unsigned* yr = y2 + (size_t)px * 48;
#pragma unroll
    for (int j = 0; j < 12; j++) {
        int c = j * 8;
        uint4 pk;
        pk.x = pack2bf((v[c + 0] - mu) * inv * w[c + 0] + bln[c + 0],
                       (v[c + 1] - mu) * inv * w[c + 1] + bln[c + 1]);
        pk.y = pack2bf((v[c + 2] - mu) * inv * w[c + 2] + bln[c + 2],
                       (v[c + 3] - mu) * inv * w[c + 3] + bln[c + 3]);
        pk.z = pack2bf((v[c + 4] - mu) * inv * w[c + 4] + bln[c + 4],
                       (v[c + 5] - mu) * inv * w[c + 5] + bln[c + 5]);
        pk.w = pack2bf((v[c + 6] - mu) * inv * w[c + 6] + bln[c + 6],
                       (v[c + 7] - mu) * inv * w[c + 7] + bln[c + 7]);
        ((uint4*)yr)[j] = pk;
    }
}

// ------------------------------------------------ final: out = x + pout + mlp (planar)
__global__ __launch_bounds__(256) void k_final(const float* __restrict__ x,
                                               const unsigned short* __restrict__ pout,
                                               const unsigned short* __restrict__ mlp,
                                               float* __restrict__ out) {
    int px = blockIdx.x * 256 + threadIdx.x;
    int b = px >> 14, pix = px & 16383;
    const float* xp = x + (size_t)b * 96 * HW16K + pix;
    float* op = out + (size_t)b * 96 * HW16K + pix;
    const uint4* pr = (const uint4*)(pout + (size_t)px * 96);
    const uint4* mr = (const uint4*)(mlp + (size_t)px * 96);
#pragma unroll
    for (int i = 0; i < 12; i++) {
        uint4 tp = pr[i], tm = mr[i];
        unsigned wpx[4] = {tp.x, tp.y, tp.z, tp.w};
        unsigned wmx[4] = {tm.x, tm.y, tm.z, tm.w};
#pragma unroll
        for (int u = 0; u < 4; u++) {
            int c = i * 8 + u * 2;
            op[(size_t)c * HW16K] = xp[(size_t)c * HW16K]
                + bf2f((unsigned short)(wpx[u] & 0xffffu))
                + bf2f((unsigned short)(wmx[u] & 0xffffu));
            op[(size_t)(c + 1) * HW16K] = xp[(size_t)(c + 1) * HW16K]
                + bf2f((unsigned short)(wpx[u] >> 16))
                + bf2f((unsigned short)(wmx[u] >> 16));
        }
    }
}

// ------------------------------------------------ launch
extern "C" void kernel_launch(void* const* d_in, const int* in_sizes, int n_in,
                              void* d_out, int out_size, void* d_ws, size_t ws_size,
                              hipStream_t stream) {
    const float* x      = (const float*)d_in[0];
    const float* qkv_w  = (const float*)d_in[1];
    const float* proj_w = (const float*)d_in[2];
    const float* proj_b = (const float*)d_in[3];
    const float* ln1w   = (const float*)d_in[4];
    const float* ln1b   = (const float*)d_in[5];
    const float* ln2w   = (const float*)d_in[6];
    const float* ln2b   = (const float*)d_in[7];
    const float* fc1w   = (const float*)d_in[8];
    const float* fc1b   = (const float*)d_in[9];
    const float* fc2w   = (const float*)d_in[10];
    const float* fc2b   = (const float*)d_in[11];
    float* out = (float*)d_out;

    char* ws = (char*)d_ws;
    unsigned short* wq = (unsigned short*)(ws);              // 55296 B
    unsigned short* wp = (unsigned short*)(ws + 55296);      // 18432 B
    unsigned short* w1 = (unsigned short*)(ws + 73728);      // 73728 B
    unsigned short* w2 = (unsigned short*)(ws + 147456);     // 73728 B
    // region Y (25.17 MB): y -> attnb -> y2 -> mlp_out
    unsigned short* y    = (unsigned short*)(ws + 221184);
    // region Q (75.5 MB): qkvb; after attention it is dead and hosts pout|h
    unsigned short* qkvb = (unsigned short*)(ws + 25387008);
    unsigned short* pout = qkvb;                              // 25.17 MB
    unsigned short* h    = (unsigned short*)(ws + 50552832);  // 25.17 MB
    // total ws = 100884480 B (~101 MB)

    k_prep<<<432, 256, 0, stream>>>(qkv_w, proj_w, fc1w, fc2w, wq, wp, w1, w2);
    k_ln1<<<1024, 256, 0, stream>>>(x, ln1w, ln1b, (unsigned*)y);

    // qkv GEMM, full M, planar qkv output (EPI 3)
    k_gemm<288, 96, 8, 2, 3><<<512, 512, 0, stream>>>(y, wq, nullptr, qkvb);
    // attention, full M; attnb reuses region Y (y is dead after qkv GEMM)
    k_attn<<<3072, 256, 0, stream>>>(qkvb, y);
    // proj (+bias) -> pout bf16 pixel-major (qkvb dead, reuse)
    k_gemm<96, 96, 8, 1, 1><<<1024, 512, 0, stream>>>(y, wp, proj_b, pout);
    // residual + LN2 -> y2 (region Y)
    k_res_ln2<<<512, 256, 0, stream>>>(x, pout, ln2w, ln2b, (unsigned*)y);

    // MLP: 4 chunks of 32768 pixels; h chunk stays L2/L3-resident,
    // mlp_out overwrites the already-consumed y2 chunk in region Y.
    for (int c = 0; c < 4; c++) {
        size_t m0 = (size_t)c * 32768;
        k_gemm<384, 96, 8, 1, 2><<<256, 512, 0, stream>>>(y + m0 * 96, w1, fc1b, h);
        k_gemm<96, 384, 8, 1, 1><<<256, 512, 0, stream>>>(h, w2, fc2b, y + m0 * 96);
    }
    // out = x + pout + mlp, all coalesced
    k_final<<<512, 256, 0, stream>>>(x, pout, y, out);
}

// Round 3
// 324.349 us; speedup vs baseline: 1.9771x; 1.2380x over previous
//
#include <hip/hip_runtime.h>
#include <hip/hip_bf16.h>
#include <math.h>

typedef __attribute__((ext_vector_type(8))) short bf16x8;
typedef __attribute__((ext_vector_type(4))) float f32x4;

#define MTOT  131072
#define HW16K 16384
#define CHUNK 65536

__device__ inline float bf2f(unsigned short u) {
    union { unsigned u; float f; } x; x.u = ((unsigned)u) << 16; return x.f;
}
__device__ inline unsigned short f2bf(float a) {
    __hip_bfloat16 h = __float2bfloat16(a);
    union { __hip_bfloat16 h; unsigned short u; } c; c.h = h; return c.u;
}
__device__ inline unsigned pack2bf(float a, float b) {
    __hip_bfloat162 h = __float22bfloat162_rn(make_float2(a, b));
    union { __hip_bfloat162 h; unsigned u; } c; c.h = h; return c.u;
}
__device__ inline void load16(const unsigned short* p, float* f) {
    uint4 u0 = *(const uint4*)p;
    uint4 u1 = *(const uint4*)(p + 8);
    unsigned w[8] = {u0.x, u0.y, u0.z, u0.w, u1.x, u1.y, u1.z, u1.w};
#pragma unroll
    for (int i = 0; i < 8; i++) {
        union { unsigned u; float f; } lo, hi;
        lo.u = w[i] << 16; hi.u = w[i] & 0xffff0000u;
        f[2 * i] = lo.f; f[2 * i + 1] = hi.f;
    }
}

// ------------------------------------------------ weights fp32 -> bf16
// qkv weight rows PERMUTED to nrow = s*96 + (di*2+hd)*16 + c so the qkv GEMM's
// 16-channel output block nt == plane s*6+g of the planar qkv buffer.
__global__ __launch_bounds__(256) void k_prep(const float* __restrict__ qw,
                                              const float* __restrict__ pw,
                                              const float* __restrict__ f1,
                                              const float* __restrict__ f2,
                                              unsigned short* __restrict__ wq,
                                              unsigned short* __restrict__ wp,
                                              unsigned short* __restrict__ w1,
                                              unsigned short* __restrict__ w2) {
    int t = blockIdx.x * 256 + threadIdx.x;
    if (t < 27648) {
        int row = t / 96, col = t - row * 96;
        int s = row / 96;            // 0=q 1=k 2=v
        int rem = row - s * 96;
        int di = rem >> 5;
        int hd = (rem >> 4) & 1;
        int c  = rem & 15;
        int nrow = s * 96 + (di * 2 + hd) * 16 + c;   // plane (s*6+g), chan c
        wq[nrow * 96 + col] = f2bf(qw[t]);
    }
    else if (t < 36864) wp[t - 27648] = f2bf(pw[t - 27648]);
    else if (t < 73728) w1[t - 36864] = f2bf(f1[t - 36864]);
    else if (t < 110592) w2[t - 73728] = f2bf(f2[t - 73728]);
}

// ------------------------------------------------ LN1: planar x fp32 -> planar-16 y bf16
__global__ __launch_bounds__(256) void k_ln1(const float* __restrict__ x,
                                             const float* __restrict__ w,
                                             const float* __restrict__ bln,
                                             unsigned* __restrict__ y) {
    __shared__ float buf[128 * 97];
    __shared__ float ps[256], ps2[256];
    int tid = threadIdx.x;
    int p = tid & 127, half = tid >> 7;
    int gp0 = blockIdx.x * 128;
    int b = gp0 >> 14, pix0 = gp0 & 16383;

    float val[48];
    float s = 0.f, s2 = 0.f;
#pragma unroll
    for (int i = 0; i < 48; i++) {
        int c = half * 48 + i;
        float v = x[((size_t)b * 96 + c) * HW16K + pix0 + p];
        val[i] = v; s += v; s2 += v * v;
    }
    ps[tid] = s; ps2[tid] = s2;
    __syncthreads();
    float st = ps[p] + ps[p + 128];
    float st2 = ps2[p] + ps2[p + 128];
    float mu = st * (1.f / 96.f);
    float inv = rsqrtf(st2 * (1.f / 96.f) - mu * mu + 1e-5f);
#pragma unroll
    for (int i = 0; i < 48; i++) {
        int c = half * 48 + i;
        buf[p * 97 + c] = (val[i] - mu) * inv * w[c] + bln[c];
    }
    __syncthreads();
    // planar store: 6 planes x 128 px x 8 uints, coalesced per plane
#pragma unroll 1
    for (int it = 0; it < 24; it++) {
        int u = it * 256 + tid;           // 0..6143
        int pl = u >> 10;                 // plane 0..5
        int rem = u & 1023;
        int pp = rem >> 3;                // pixel 0..127
        int c2 = rem & 7;                 // uint within row
        float f0 = buf[pp * 97 + pl * 16 + c2 * 2];
        float f1 = buf[pp * 97 + pl * 16 + c2 * 2 + 1];
        y[((size_t)pl * MTOT + gp0 + pp) * 8 + c2] = pack2bf(f0, f1);
    }
}

// ------------------------------------------------ MFMA GEMM, planar-16 A and out.
// A planar: plane pa holds A-channels pa*16..pa*16+15, row px, 16 bf16/row.
// Bw: [N][K] bf16 row-major (weights). Bs rows padded K -> K+8 (bank phases).
// mfma(W_frag, P_frag): lane holds px = lane&15, och = nt*16 + q*4 + r.
// Store: plane nt, 8B uint2 per lane -> one 512B region per instruction.
// EPI: 0 = store; 1 = +bias; 2 = +bias +GeLU.
template<int N, int K, int NW, int TPW, int EPI>
__global__ __launch_bounds__(NW * 64) void k_gemm(const unsigned short* __restrict__ A,
                                                  const unsigned short* __restrict__ Bw,
                                                  const float* __restrict__ bias,
                                                  unsigned short* __restrict__ out,
                                                  int am0, int MA, int om0, int MO) {
    constexpr int KF = K / 32, NT = N / 16, KP = K + 8;
    __shared__ unsigned short Bs[N * KP];
    int tid = threadIdx.x;
    for (int i = tid; i < N * (K / 8); i += NW * 64) {
        int row = i / (K / 8), col = i - row * (K / 8);
        *(uint4*)(Bs + row * KP + col * 8) = ((const uint4*)Bw)[i];
    }
    __syncthreads();

    int lane = tid & 63, wv = tid >> 6;
    int q = lane >> 4, l15 = lane & 15;

#pragma unroll 1
    for (int it = 0; it < TPW; it++) {
        int pt = blockIdx.x * (NW * TPW) + wv * TPW + it;
        int px = pt * 16 + l15;

        bf16x8 p[KF];
#pragma unroll
        for (int f = 0; f < KF; f++) {
            int pa = 2 * f + (q >> 1);
            p[f] = *(const bf16x8*)(A + ((size_t)pa * MA + am0 + px) * 16 + (q & 1) * 8);
        }

        f32x4 acc[NT];
#pragma unroll
        for (int nt = 0; nt < NT; nt++) acc[nt] = (f32x4){0.f, 0.f, 0.f, 0.f};

#pragma unroll
        for (int nt = 0; nt < NT; nt++) {
            const unsigned short* br = Bs + (nt * 16 + l15) * KP + q * 8;
#pragma unroll
            for (int f = 0; f < KF; f++) {
                bf16x8 wf = *(const bf16x8*)(br + f * 32);
                acc[nt] = __builtin_amdgcn_mfma_f32_16x16x32_bf16(wf, p[f], acc[nt], 0, 0, 0);
            }
        }

#pragma unroll
        for (int nt = 0; nt < NT; nt++) {
            float r0 = acc[nt][0], r1 = acc[nt][1], r2 = acc[nt][2], r3 = acc[nt][3];
            if constexpr (EPI == 1 || EPI == 2) {
                float4 bb = ((const float4*)bias)[nt * 4 + q];
                r0 += bb.x; r1 += bb.y; r2 += bb.z; r3 += bb.w;
            }
            if constexpr (EPI == 2) {
                r0 = 0.5f * r0 * (1.f + erff(r0 * 0.70710678118654752f));
                r1 = 0.5f * r1 * (1.f + erff(r1 * 0.70710678118654752f));
                r2 = 0.5f * r2 * (1.f + erff(r2 * 0.70710678118654752f));
                r3 = 0.5f * r3 * (1.f + erff(r3 * 0.70710678118654752f));
            }
            uint2 pk;
            pk.x = pack2bf(r0, r1);
            pk.y = pack2bf(r2, r3);
            *(uint2*)(out + ((size_t)nt * MO + om0 + px) * 16 + q * 4) = pk;
        }
    }
}

// ------------------------------------------------ dilated attention, planar qkv
// qkvb: 18 planes [pl][px][16], pl = s*6+g. attnb: 6 planes [g][px][16].
// XCD-chunked blockIdx: bid&7 (= XCD) gets a contiguous y-span per group g.
__global__ __launch_bounds__(256) void k_attn(const unsigned short* __restrict__ qkvb,
                                              unsigned short* __restrict__ attnb) {
    int bid = blockIdx.x;
    int xcd = bid & 7;
    int idx = bid >> 3;                  // 0..383
    int g   = idx >> 6;                  // 0..5
    int yb  = (xcd << 6) | (idx & 63);   // 0..511
    int px  = yb * 256 + threadIdx.x;

    int d = (g >> 1) + 1;
    int pix = px & 16383;
    int hh = pix >> 7, ww = pix & 127;
    int ibase = px & ~16383;

    const unsigned short* qpl = qkvb + (size_t)g * (MTOT * 16);
    const unsigned short* kpl = qkvb + (size_t)(6 + g) * (MTOT * 16);
    const unsigned short* vpl = qkvb + (size_t)(12 + g) * (MTOT * 16);

    float q[16];
    load16(qpl + (size_t)px * 16, q);

    float sc[9]; int nloc[9]; bool ok[9];
#pragma unroll
    for (int i = 0; i < 3; i++) {
#pragma unroll
        for (int j = 0; j < 3; j++) {
            int k9 = i * 3 + j;
            int yy = hh + (i - 1) * d;
            int xx = ww + (j - 1) * d;
            bool o_ = ((unsigned)yy < 128u) && ((unsigned)xx < 128u);
            ok[k9] = o_;
            nloc[k9] = ibase + yy * 128 + xx;
            float s = 0.f;
            if (o_) {
                float kf[16];
                load16(kpl + (size_t)nloc[k9] * 16, kf);
#pragma unroll
                for (int c = 0; c < 16; c++) s += q[c] * kf[c];
            }
            sc[k9] = s * 0.25f;
        }
    }
    float mx = sc[0];
#pragma unroll
    for (int k9 = 1; k9 < 9; k9++) mx = fmaxf(mx, sc[k9]);
    float sum = 0.f;
#pragma unroll
    for (int k9 = 0; k9 < 9; k9++) { sc[k9] = __expf(sc[k9] - mx); sum += sc[k9]; }
    float rs = 1.f / sum;

    float o[16];
#pragma unroll
    for (int c = 0; c < 16; c++) o[c] = 0.f;
#pragma unroll
    for (int k9 = 0; k9 < 9; k9++) {
        if (ok[k9]) {
            float vf[16];
            load16(vpl + (size_t)nloc[k9] * 16, vf);
            float w9 = sc[k9];
#pragma unroll
            for (int c = 0; c < 16; c++) o[c] += w9 * vf[c];
        }
    }
    uint4* orow = (uint4*)(attnb + ((size_t)g * MTOT + px) * 16);
    uint4 pk0;
    pk0.x = pack2bf(o[0] * rs, o[1] * rs);
    pk0.y = pack2bf(o[2] * rs, o[3] * rs);
    pk0.z = pack2bf(o[4] * rs, o[5] * rs);
    pk0.w = pack2bf(o[6] * rs, o[7] * rs);
    orow[0] = pk0;
    uint4 pk1;
    pk1.x = pack2bf(o[8] * rs, o[9] * rs);
    pk1.y = pack2bf(o[10] * rs, o[11] * rs);
    pk1.z = pack2bf(o[12] * rs, o[13] * rs);
    pk1.w = pack2bf(o[14] * rs, o[15] * rs);
    orow[1] = pk1;
}

// ------------------------------------------------ residual + LN2 fused, all planar.
__global__ __launch_bounds__(256) void k_res_ln2(const float* __restrict__ x,
                                                 const unsigned short* __restrict__ pout,
                                                 const float* __restrict__ w,
                                                 const float* __restrict__ bln,
                                                 unsigned short* __restrict__ y2) {
    int px = blockIdx.x * 256 + threadIdx.x;
    int b = px >> 14, pix = px & 16383;
    const float* xp = x + (size_t)b * 96 * HW16K + pix;
    float v[96];
    float s = 0.f, s2 = 0.f;
#pragma unroll
    for (int pl = 0; pl < 6; pl++) {
        const uint4* pr = (const uint4*)(pout + ((size_t)pl * MTOT + px) * 16);
        uint4 t0 = pr[0], t1 = pr[1];
        unsigned wd[8] = {t0.x, t0.y, t0.z, t0.w, t1.x, t1.y, t1.z, t1.w};
#pragma unroll
        for (int u = 0; u < 8; u++) {
            int c = pl * 16 + u * 2;
            float v0 = bf2f((unsigned short)(wd[u] & 0xffffu)) + xp[(size_t)c * HW16K];
            float v1 = bf2f((unsigned short)(wd[u] >> 16)) + xp[(size_t)(c + 1) * HW16K];
            v[c] = v0; v[c + 1] = v1;
            s += v0 + v1; s2 += v0 * v0 + v1 * v1;
        }
    }
    float mu = s * (1.f / 96.f);
    float inv = rsqrtf(s2 * (1.f / 96.f) - mu * mu + 1e-5f);
#pragma unroll
    for (int pl = 0; pl < 6; pl++) {
        uint4 pk0, pk1;
        int c = pl * 16;
        pk0.x = pack2bf((v[c + 0] - mu) * inv * w[c + 0] + bln[c + 0],
                        (v[c + 1] - mu) * inv * w[c + 1] + bln[c + 1]);
        pk0.y = pack2bf((v[c + 2] - mu) * inv * w[c + 2] + bln[c + 2],
                        (v[c + 3] - mu) * inv * w[c + 3] + bln[c + 3]);
        pk0.z = pack2bf((v[c + 4] - mu) * inv * w[c + 4] + bln[c + 4],
                        (v[c + 5] - mu) * inv * w[c + 5] + bln[c + 5]);
        pk0.w = pack2bf((v[c + 6] - mu) * inv * w[c + 6] + bln[c + 6],
                        (v[c + 7] - mu) * inv * w[c + 7] + bln[c + 7]);
        pk1.x = pack2bf((v[c + 8] - mu) * inv * w[c + 8] + bln[c + 8],
                        (v[c + 9] - mu) * inv * w[c + 9] + bln[c + 9]);
        pk1.y = pack2bf((v[c + 10] - mu) * inv * w[c + 10] + bln[c + 10],
                        (v[c + 11] - mu) * inv * w[c + 11] + bln[c + 11]);
        pk1.z = pack2bf((v[c + 12] - mu) * inv * w[c + 12] + bln[c + 12],
                        (v[c + 13] - mu) * inv * w[c + 13] + bln[c + 13]);
        pk1.w = pack2bf((v[c + 14] - mu) * inv * w[c + 14] + bln[c + 14],
                        (v[c + 15] - mu) * inv * w[c + 15] + bln[c + 15]);
        uint4* yr = (uint4*)(y2 + ((size_t)pl * MTOT + px) * 16);
        yr[0] = pk0; yr[1] = pk1;
    }
}

// ------------------------------------------------ final: out = x + pout + mlp (planar)
__global__ __launch_bounds__(256) void k_final(const float* __restrict__ x,
                                               const unsigned short* __restrict__ pout,
                                               const unsigned short* __restrict__ mlp,
                                               float* __restrict__ out) {
    int px = blockIdx.x * 256 + threadIdx.x;
    int b = px >> 14, pix = px & 16383;
    const float* xp = x + (size_t)b * 96 * HW16K + pix;
    float* op = out + (size_t)b * 96 * HW16K + pix;
#pragma unroll
    for (int pl = 0; pl < 6; pl++) {
        const uint4* pr = (const uint4*)(pout + ((size_t)pl * MTOT + px) * 16);
        const uint4* mr = (const uint4*)(mlp + ((size_t)pl * MTOT + px) * 16);
        uint4 tp0 = pr[0], tp1 = pr[1];
        uint4 tm0 = mr[0], tm1 = mr[1];
        unsigned wpx[8] = {tp0.x, tp0.y, tp0.z, tp0.w, tp1.x, tp1.y, tp1.z, tp1.w};
        unsigned wmx[8] = {tm0.x, tm0.y, tm0.z, tm0.w, tm1.x, tm1.y, tm1.z, tm1.w};
#pragma unroll
        for (int u = 0; u < 8; u++) {
            int c = pl * 16 + u * 2;
            op[(size_t)c * HW16K] = xp[(size_t)c * HW16K]
                + bf2f((unsigned short)(wpx[u] & 0xffffu))
                + bf2f((unsigned short)(wmx[u] & 0xffffu));
            op[(size_t)(c + 1) * HW16K] = xp[(size_t)(c + 1) * HW16K]
                + bf2f((unsigned short)(wpx[u] >> 16))
                + bf2f((unsigned short)(wmx[u] >> 16));
        }
    }
}

// ------------------------------------------------ launch
extern "C" void kernel_launch(void* const* d_in, const int* in_sizes, int n_in,
                              void* d_out, int out_size, void* d_ws, size_t ws_size,
                              hipStream_t stream) {
    const float* x      = (const float*)d_in[0];
    const float* qkv_w  = (const float*)d_in[1];
    const float* proj_w = (const float*)d_in[2];
    const float* proj_b = (const float*)d_in[3];
    const float* ln1w   = (const float*)d_in[4];
    const float* ln1b   = (const float*)d_in[5];
    const float* ln2w   = (const float*)d_in[6];
    const float* ln2b   = (const float*)d_in[7];
    const float* fc1w   = (const float*)d_in[8];
    const float* fc1b   = (const float*)d_in[9];
    const float* fc2w   = (const float*)d_in[10];
    const float* fc2b   = (const float*)d_in[11];
    float* out = (float*)d_out;

    char* ws = (char*)d_ws;
    unsigned short* wq = (unsigned short*)(ws);              // 55296 B
    unsigned short* wp = (unsigned short*)(ws + 55296);      // 18432 B
    unsigned short* w1 = (unsigned short*)(ws + 73728);      // 73728 B
    unsigned short* w2 = (unsigned short*)(ws + 147456);     // 73728 B
    // region A (25.17 MB): y -> attnb -> y2 -> mlp_out  (6 planes x MTOT x 16 bf16)
    unsigned short* rA   = (unsigned short*)(ws + 221184);
    // region B (75.5 MB): qkvb (18 planes); after attn: pout (6 planes) + h chunk
    unsigned short* qkvb = (unsigned short*)(ws + 25387008);
    unsigned short* pout = qkvb;                              // 25.17 MB
    unsigned short* h    = (unsigned short*)(ws + 50552832);  // 50.33 MB (24 planes x CHUNK x 16)
    // total ws = 100884480 B (~101 MB)

    k_prep<<<432, 256, 0, stream>>>(qkv_w, proj_w, fc1w, fc2w, wq, wp, w1, w2);
    k_ln1<<<1024, 256, 0, stream>>>(x, ln1w, ln1b, (unsigned*)rA);

    // qkv GEMM, full M, planar in/out
    k_gemm<288, 96, 8, 2, 0><<<512, 512, 0, stream>>>(rA, wq, nullptr, qkvb,
                                                      0, MTOT, 0, MTOT);
    // attention, full M; attnb reuses region A (y dead after qkv GEMM)
    k_attn<<<3072, 256, 0, stream>>>(qkvb, rA);
    // proj (+bias) -> pout planar (qkvb dead, reuse)
    k_gemm<96, 96, 8, 1, 1><<<1024, 512, 0, stream>>>(rA, wp, proj_b, pout,
                                                      0, MTOT, 0, MTOT);
    // residual + LN2 -> y2 (region A)
    k_res_ln2<<<512, 256, 0, stream>>>(x, pout, ln2w, ln2b, rA);

    // MLP: 2 chunks of 65536 pixels; h chunk L2/L3-resident planar-24.
    // fc2 writes mlp into the consumed y2 chunk range of region A.
    for (int c = 0; c < 2; c++) {
        int m0 = c * CHUNK;
        k_gemm<384, 96, 8, 1, 2><<<512, 512, 0, stream>>>(rA, w1, fc1b, h,
                                                          m0, MTOT, 0, CHUNK);
        k_gemm<96, 384, 8, 1, 1><<<512, 512, 0, stream>>>(h, w2, fc2b, rA,
                                                          0, CHUNK, m0, MTOT);
    }
    // out = x + pout + mlp, all coalesced
    k_final<<<512, 256, 0, stream>>>(x, pout, rA, out);
}